// Round 1
// baseline (2119.488 us; speedup 1.0000x reference)
//
#include <hip/hip_runtime.h>
#include <math.h>

#define SEQ    2048
#define BSZ    2
#define DMODEL 1024
#define DINNER 2048
#define DSTATE 16
#define DTRANK 64
#define MTOT   (BSZ*SEQ)   // 4096

// ---------------- generic fp32 tiled GEMM (64x64 tile, 16 K-slice) ----------------
// C[M,N] = A[M,K] @ B[K,N]   (row-major, arbitrary leading dims)
// EPI: 0 = plain store, 1 = softplus(acc + bias[col])
template<int EPI>
__global__ __launch_bounds__(256)
void gemm_f32(const float* __restrict__ A, const float* __restrict__ B,
              float* __restrict__ C, const float* __restrict__ bias,
              int M, int N, int K, int lda, int ldb, int ldc)
{
    __shared__ float As[16][68];   // transposed: As[k][m]  (68 = 64+4 pad, keeps 16B align)
    __shared__ float Bs[16][68];   // Bs[k][n]
    const int tid = threadIdx.x;
    const int tx = tid & 15, ty = tid >> 4;
    const int m0 = blockIdx.y * 64, n0 = blockIdx.x * 64;
    const int arow = tid >> 2, acol = (tid & 3) << 2;   // A-stage: 64 rows x 16 k
    const int brow = tid >> 4, bcol = (tid & 15) << 2;  // B-stage: 16 k x 64 n
    float acc[4][4] = {{0.f,0.f,0.f,0.f},{0.f,0.f,0.f,0.f},
                       {0.f,0.f,0.f,0.f},{0.f,0.f,0.f,0.f}};

    for (int k0 = 0; k0 < K; k0 += 16) {
        // M is always a multiple of 64 and K a multiple of 16 in this problem.
        float4 av = *(const float4*)(A + (size_t)(m0 + arow) * lda + k0 + acol);
        float4 bv = make_float4(0.f, 0.f, 0.f, 0.f);
        if (n0 + bcol < N)   // all N used are multiples of 4, so col<N => col+3<N
            bv = *(const float4*)(B + (size_t)(k0 + brow) * ldb + n0 + bcol);
        __syncthreads();
        As[acol+0][arow] = av.x;
        As[acol+1][arow] = av.y;
        As[acol+2][arow] = av.z;
        As[acol+3][arow] = av.w;
        *(float4*)&Bs[brow][bcol] = bv;
        __syncthreads();
        #pragma unroll
        for (int kk = 0; kk < 16; ++kk) {
            float4 a = *(const float4*)&As[kk][ty << 2];
            float4 b = *(const float4*)&Bs[kk][tx << 2];
            float ar[4] = {a.x, a.y, a.z, a.w};
            float br[4] = {b.x, b.y, b.z, b.w};
            #pragma unroll
            for (int i = 0; i < 4; ++i)
                #pragma unroll
                for (int j = 0; j < 4; ++j)
                    acc[i][j] = fmaf(ar[i], br[j], acc[i][j]);
        }
    }

    const int col = n0 + (tx << 2);
    if (col >= N) return;
    #pragma unroll
    for (int i = 0; i < 4; ++i) {
        const int row = m0 + (ty << 2) + i;
        float r[4] = {acc[i][0], acc[i][1], acc[i][2], acc[i][3]};
        if (EPI == 1) {
            #pragma unroll
            for (int j = 0; j < 4; ++j) {
                float xb = r[j] + bias[col + j];
                // numerically-stable softplus
                r[j] = fmaxf(xb, 0.f) + log1pf(expf(-fabsf(xb)));
            }
        }
        float4 o; o.x = r[0]; o.y = r[1]; o.z = r[2]; o.w = r[3];
        *(float4*)(C + (size_t)row * ldc + col) = o;
    }
}

// ---------------- causal depthwise conv (k=4) + silu ----------------
__global__ __launch_bounds__(256)
void conv_silu_k(const float* __restrict__ xz, const float* __restrict__ wconv,
                 const float* __restrict__ bconv, float* __restrict__ xc)
{
    const int idx = blockIdx.x * 256 + threadIdx.x;  // over MTOT*DINNER
    const int d   = idx & (DINNER - 1);
    const int row = idx >> 11;          // b*SEQ + l
    const int l   = row & (SEQ - 1);
    const float4 w = *(const float4*)(wconv + d * 4);
    const float wk[4] = {w.x, w.y, w.z, w.w};
    float acc = bconv[d];
    const float* xp = xz + (size_t)row * (2 * DINNER) + d;   // x half: cols [0,2048)
    #pragma unroll
    for (int k = 0; k < 4; ++k) {
        const int ls = l - 3 + k;
        if (ls >= 0) acc = fmaf(xp[(k - 3) * (2 * DINNER)], wk[k], acc);
    }
    xc[idx] = acc / (1.f + expf(-acc));   // silu
}

// ---------------- selective scan (16 lanes per (b,d) channel, unroll 8) ----------------
__global__ __launch_bounds__(256)
void scan_k(const float* __restrict__ dtb, const float* __restrict__ xc,
            const float* __restrict__ dbc, const float* __restrict__ xz,
            const float* __restrict__ A_log, const float* __restrict__ Dvec,
            float* __restrict__ y)
{
    const int t = blockIdx.x * 256 + threadIdx.x;   // 65536 threads
    const int n = t & 15;
    const int g = t >> 4;          // (b,d) channel, 0..4095
    const int d = g & (DINNER - 1);
    const int b = g >> 11;
    const float a  = -expf(A_log[d * DSTATE + n]);
    const float Dv = Dvec[d];
    float h = 0.f;

    const float* dtp = dtb + (size_t)b * SEQ * DINNER + d;
    const float* xcp = xc  + (size_t)b * SEQ * DINNER + d;
    const float* zp  = xz  + (size_t)b * SEQ * (2 * DINNER) + DINNER + d;
    const float* bp  = dbc + (size_t)b * SEQ * 96 + DTRANK + n;
    const float* cp  = dbc + (size_t)b * SEQ * 96 + DTRANK + DSTATE + n;
    float*       yp  = y   + (size_t)b * SEQ * DINNER + d;

    for (int l = 0; l < SEQ; l += 8) {
        float dtv[8], xv[8], Bv[8], Cv[8];
        #pragma unroll
        for (int j = 0; j < 8; ++j) {
            dtv[j] = dtp[(size_t)(l + j) * DINNER];
            xv[j]  = xcp[(size_t)(l + j) * DINNER];
            Bv[j]  = bp[(size_t)(l + j) * 96];
            Cv[j]  = cp[(size_t)(l + j) * 96];
        }
        #pragma unroll
        for (int j = 0; j < 8; ++j) {
            h = expf(dtv[j] * a) * h + (xv[j] * dtv[j]) * Bv[j];
            float p = Cv[j] * h;
            p += __shfl_xor(p, 1);
            p += __shfl_xor(p, 2);
            p += __shfl_xor(p, 4);
            p += __shfl_xor(p, 8);
            if (n == 0) {
                const float zv = zp[(size_t)(l + j) * (2 * DINNER)];
                const float s  = zv / (1.f + expf(-zv));
                yp[(size_t)(l + j) * DINNER] = (p + xv[j] * Dv) * s;
            }
        }
    }
}

extern "C" void kernel_launch(void* const* d_in, const int* in_sizes, int n_in,
                              void* d_out, int out_size, void* d_ws, size_t ws_size,
                              hipStream_t stream)
{
    const float* x      = (const float*)d_in[0];
    const float* w_in   = (const float*)d_in[1];
    const float* w_conv = (const float*)d_in[2];
    const float* b_conv = (const float*)d_in[3];
    const float* w_xproj= (const float*)d_in[4];
    const float* w_dt   = (const float*)d_in[5];
    const float* b_dt   = (const float*)d_in[6];
    const float* A_log  = (const float*)d_in[7];
    const float* Dvec   = (const float*)d_in[8];
    const float* w_out  = (const float*)d_in[9];
    float* out = (float*)d_out;

    float* ws  = (float*)d_ws;
    float* xz  = ws;                                  // [4096,4096]  67.1 MB
    float* xc  = xz  + (size_t)MTOT * 2 * DINNER;     // [4096,2048]  33.5 MB
    float* dbc = xc  + (size_t)MTOT * DINNER;         // [4096,96]     1.6 MB
    float* dtb = dbc + (size_t)MTOT * 96;             // [4096,2048]  33.5 MB
    float* yp  = dtb + (size_t)MTOT * DINNER;         // [4096,2048]  33.5 MB

    // 1) in-projection: xz = x @ w_in          [4096,1024]@[1024,4096]
    gemm_f32<0><<<dim3(64, 64), 256, 0, stream>>>(
        x, w_in, xz, nullptr, MTOT, 2 * DINNER, DMODEL, DMODEL, 2 * DINNER, 2 * DINNER);

    // 2) causal conv + silu -> xc
    conv_silu_k<<<(MTOT * DINNER) / 256, 256, 0, stream>>>(xz, w_conv, b_conv, xc);

    // 3) x_dbc = xc @ w_xproj                  [4096,2048]@[2048,96]
    gemm_f32<0><<<dim3(2, 64), 256, 0, stream>>>(
        xc, w_xproj, dbc, nullptr, MTOT, 96, DINNER, DINNER, 96, 96);

    // 4) dt = softplus(x_dbc[:, :64] @ w_dt + b_dt)   [4096,64]@[64,2048]
    gemm_f32<1><<<dim3(32, 64), 256, 0, stream>>>(
        dbc, w_dt, dtb, b_dt, MTOT, DINNER, DTRANK, 96, DINNER, DINNER);

    // 5) selective scan + gating -> yp
    scan_k<<<256, 256, 0, stream>>>(dtb, xc, dbc, xz, A_log, Dvec, yp);

    // 6) out-projection: out = yp @ w_out      [4096,2048]@[2048,1024]
    gemm_f32<0><<<dim3(16, 64), 256, 0, stream>>>(
        yp, w_out, out, nullptr, MTOT, DMODEL, DINNER, DINNER, DMODEL, DMODEL);
}

// Round 2
// 1199.897 us; speedup vs baseline: 1.7664x; 1.7664x over previous
//
#include <hip/hip_runtime.h>
#include <math.h>

#define SEQ    2048
#define BSZ    2
#define DMODEL 1024
#define DINNER 2048
#define DSTATE 16
#define DTRANK 64
#define MTOT   (BSZ*SEQ)   // 4096
#define NCHUNK 16
#define LC     (SEQ/NCHUNK)   // 128
#define BDN    (BSZ*DINNER*DSTATE)  // 65536

// ---------------- generic fp32 tiled GEMM (64x64 tile, 16 K-slice) ----------------
// C[M,N] = A[M,K] @ B[K,N]   (row-major, arbitrary leading dims)
// EPI: 0 = plain store, 1 = softplus(acc + bias[col])
template<int EPI>
__global__ __launch_bounds__(256)
void gemm_f32(const float* __restrict__ A, const float* __restrict__ B,
              float* __restrict__ C, const float* __restrict__ bias,
              int M, int N, int K, int lda, int ldb, int ldc)
{
    __shared__ float As[16][68];   // transposed: As[k][m]
    __shared__ float Bs[16][68];   // Bs[k][n]
    const int tid = threadIdx.x;
    const int tx = tid & 15, ty = tid >> 4;
    const int m0 = blockIdx.y * 64, n0 = blockIdx.x * 64;
    const int arow = tid >> 2, acol = (tid & 3) << 2;   // A-stage: 64 rows x 16 k
    const int brow = tid >> 4, bcol = (tid & 15) << 2;  // B-stage: 16 k x 64 n
    float acc[4][4] = {{0.f,0.f,0.f,0.f},{0.f,0.f,0.f,0.f},
                       {0.f,0.f,0.f,0.f},{0.f,0.f,0.f,0.f}};

    for (int k0 = 0; k0 < K; k0 += 16) {
        float4 av = *(const float4*)(A + (size_t)(m0 + arow) * lda + k0 + acol);
        float4 bv = make_float4(0.f, 0.f, 0.f, 0.f);
        if (n0 + bcol < N)
            bv = *(const float4*)(B + (size_t)(k0 + brow) * ldb + n0 + bcol);
        __syncthreads();
        As[acol+0][arow] = av.x;
        As[acol+1][arow] = av.y;
        As[acol+2][arow] = av.z;
        As[acol+3][arow] = av.w;
        *(float4*)&Bs[brow][bcol] = bv;
        __syncthreads();
        #pragma unroll
        for (int kk = 0; kk < 16; ++kk) {
            float4 a = *(const float4*)&As[kk][ty << 2];
            float4 b = *(const float4*)&Bs[kk][tx << 2];
            float ar[4] = {a.x, a.y, a.z, a.w};
            float br[4] = {b.x, b.y, b.z, b.w};
            #pragma unroll
            for (int i = 0; i < 4; ++i)
                #pragma unroll
                for (int j = 0; j < 4; ++j)
                    acc[i][j] = fmaf(ar[i], br[j], acc[i][j]);
        }
    }

    const int col = n0 + (tx << 2);
    if (col >= N) return;
    #pragma unroll
    for (int i = 0; i < 4; ++i) {
        const int row = m0 + (ty << 2) + i;
        float r[4] = {acc[i][0], acc[i][1], acc[i][2], acc[i][3]};
        if (EPI == 1) {
            #pragma unroll
            for (int j = 0; j < 4; ++j) {
                float xb = r[j] + bias[col + j];
                r[j] = fmaxf(xb, 0.f) + log1pf(expf(-fabsf(xb)));
            }
        }
        float4 o; o.x = r[0]; o.y = r[1]; o.z = r[2]; o.w = r[3];
        *(float4*)(C + (size_t)row * ldc + col) = o;
    }
}

// ---------------- causal depthwise conv (k=4) + silu ----------------
__global__ __launch_bounds__(256)
void conv_silu_k(const float* __restrict__ xz, const float* __restrict__ wconv,
                 const float* __restrict__ bconv, float* __restrict__ xc)
{
    const int idx = blockIdx.x * 256 + threadIdx.x;  // over MTOT*DINNER
    const int d   = idx & (DINNER - 1);
    const int row = idx >> 11;          // b*SEQ + l
    const int l   = row & (SEQ - 1);
    const float4 w = *(const float4*)(wconv + d * 4);
    const float wk[4] = {w.x, w.y, w.z, w.w};
    float acc = bconv[d];
    const float* xp = xz + (size_t)row * (2 * DINNER) + d;   // x half
    #pragma unroll
    for (int k = 0; k < 4; ++k) {
        const int ls = l - 3 + k;
        if (ls >= 0) acc = fmaf(xp[(k - 3) * (2 * DINNER)], wk[k], acc);
    }
    xc[idx] = acc / (1.f + expf(-acc));   // silu
}

// ---------------- chunked selective scan ----------------
// Phase A: per (chunk, b, d, n) compute chunk-local final state S (h0=0)
//          and log of chunk decay Pl = a * sum(dt). Layout: [c][bdn].
__global__ __launch_bounds__(256)
void scan_phase_a(const float* __restrict__ dtb, const float* __restrict__ xc,
                  const float* __restrict__ dbc, const float* __restrict__ A_log,
                  float* __restrict__ S, float* __restrict__ Pl)
{
    const int tid = blockIdx.x * 256 + threadIdx.x;   // BDN*NCHUNK = 1M
    const int bdn = tid & (BDN - 1);
    const int c   = tid >> 16;
    const int n = bdn & 15;
    const int d = (bdn >> 4) & (DINNER - 1);
    const int b = bdn >> 15;
    const float a = -expf(A_log[d * DSTATE + n]);
    const int r0 = b * SEQ + c * LC;
    const float* dtp = dtb + (size_t)r0 * DINNER + d;
    const float* xcp = xc  + (size_t)r0 * DINNER + d;
    const float* bp  = dbc + (size_t)r0 * 96 + DTRANK + n;
    float h = 0.f, sdt = 0.f;
    for (int l = 0; l < LC; l += 8) {
        float dtv[8], xv[8], Bv[8];
        #pragma unroll
        for (int j = 0; j < 8; ++j) {
            dtv[j] = dtp[(size_t)(l + j) * DINNER];
            xv[j]  = xcp[(size_t)(l + j) * DINNER];
            Bv[j]  = bp[(size_t)(l + j) * 96];
        }
        #pragma unroll
        for (int j = 0; j < 8; ++j) {
            sdt += dtv[j];
            h = expf(dtv[j] * a) * h + (xv[j] * dtv[j]) * Bv[j];
        }
    }
    S[tid]  = h;
    Pl[tid] = a * sdt;
}

// Phase B: serial combine over chunks -> carry-in state H[c][bdn]
__global__ __launch_bounds__(256)
void scan_phase_b(const float* __restrict__ S, const float* __restrict__ Pl,
                  float* __restrict__ H)
{
    const int bdn = blockIdx.x * 256 + threadIdx.x;  // BDN threads
    float h = 0.f;
    #pragma unroll
    for (int c = 0; c < NCHUNK; ++c) {
        H[c * BDN + bdn] = h;
        h = expf(Pl[c * BDN + bdn]) * h + S[c * BDN + bdn];
    }
}

// Phase C: re-run scan per chunk seeded with carry-in, produce gated output y
__global__ __launch_bounds__(256)
void scan_phase_c(const float* __restrict__ dtb, const float* __restrict__ xc,
                  const float* __restrict__ dbc, const float* __restrict__ xz,
                  const float* __restrict__ A_log, const float* __restrict__ Dvec,
                  const float* __restrict__ H, float* __restrict__ y)
{
    const int tid = blockIdx.x * 256 + threadIdx.x;
    const int bdn = tid & (BDN - 1);
    const int c   = tid >> 16;
    const int n = bdn & 15;
    const int d = (bdn >> 4) & (DINNER - 1);
    const int b = bdn >> 15;
    const float a  = -expf(A_log[d * DSTATE + n]);
    const float Dv = Dvec[d];
    const int r0 = b * SEQ + c * LC;
    const float* dtp = dtb + (size_t)r0 * DINNER + d;
    const float* xcp = xc  + (size_t)r0 * DINNER + d;
    const float* bp  = dbc + (size_t)r0 * 96 + DTRANK + n;
    const float* cp  = dbc + (size_t)r0 * 96 + DTRANK + DSTATE + n;
    const float* zp  = xz  + (size_t)r0 * (2 * DINNER) + DINNER + d;
    float*       yp  = y   + (size_t)r0 * DINNER + d;
    float h = H[tid];

    for (int l = 0; l < LC; l += 8) {
        float dtv[8], xv[8], Bv[8], Cv[8], p[8];
        #pragma unroll
        for (int j = 0; j < 8; ++j) {
            dtv[j] = dtp[(size_t)(l + j) * DINNER];
            xv[j]  = xcp[(size_t)(l + j) * DINNER];
            Bv[j]  = bp[(size_t)(l + j) * 96];
            Cv[j]  = cp[(size_t)(l + j) * 96];
        }
        #pragma unroll
        for (int j = 0; j < 8; ++j) {
            h = expf(dtv[j] * a) * h + (xv[j] * dtv[j]) * Bv[j];
            p[j] = Cv[j] * h;
        }
        // batched reduce: 4 stages x 8 independent shuffles (pipelined)
        #pragma unroll
        for (int m = 1; m < 16; m <<= 1) {
            #pragma unroll
            for (int j = 0; j < 8; ++j)
                p[j] += __shfl_xor(p[j], m);
        }
        if (n == 0) {
            #pragma unroll
            for (int j = 0; j < 8; ++j) {
                const float zv = zp[(size_t)(l + j) * (2 * DINNER)];
                const float s  = zv / (1.f + expf(-zv));
                yp[(size_t)(l + j) * DINNER] = (p[j] + xv[j] * Dv) * s;
            }
        }
    }
}

extern "C" void kernel_launch(void* const* d_in, const int* in_sizes, int n_in,
                              void* d_out, int out_size, void* d_ws, size_t ws_size,
                              hipStream_t stream)
{
    const float* x      = (const float*)d_in[0];
    const float* w_in   = (const float*)d_in[1];
    const float* w_conv = (const float*)d_in[2];
    const float* b_conv = (const float*)d_in[3];
    const float* w_xproj= (const float*)d_in[4];
    const float* w_dt   = (const float*)d_in[5];
    const float* b_dt   = (const float*)d_in[6];
    const float* A_log  = (const float*)d_in[7];
    const float* Dvec   = (const float*)d_in[8];
    const float* w_out  = (const float*)d_in[9];
    float* out = (float*)d_out;

    float* ws  = (float*)d_ws;
    float* xz  = ws;                                  // [4096,4096]  67.1 MB
    float* xc  = xz  + (size_t)MTOT * 2 * DINNER;     // [4096,2048]  33.5 MB
    float* dbc = xc  + (size_t)MTOT * DINNER;         // [4096,96]     1.6 MB
    float* dtb = dbc + (size_t)MTOT * 96;             // [4096,2048]  33.5 MB
    float* yp  = dtb + (size_t)MTOT * DINNER;         // [4096,2048]  33.5 MB
    float* Sb  = yp  + (size_t)MTOT * DINNER;         // [16,65536]    4.2 MB
    float* Pl  = Sb  + (size_t)NCHUNK * BDN;          // [16,65536]    4.2 MB
    float* Hc  = Pl  + (size_t)NCHUNK * BDN;          // [16,65536]    4.2 MB

    // 1) in-projection: xz = x @ w_in          [4096,1024]@[1024,4096]
    gemm_f32<0><<<dim3(64, 64), 256, 0, stream>>>(
        x, w_in, xz, nullptr, MTOT, 2 * DINNER, DMODEL, DMODEL, 2 * DINNER, 2 * DINNER);

    // 2) causal conv + silu -> xc
    conv_silu_k<<<(MTOT * DINNER) / 256, 256, 0, stream>>>(xz, w_conv, b_conv, xc);

    // 3) x_dbc = xc @ w_xproj                  [4096,2048]@[2048,96]
    gemm_f32<0><<<dim3(2, 64), 256, 0, stream>>>(
        xc, w_xproj, dbc, nullptr, MTOT, 96, DINNER, DINNER, 96, 96);

    // 4) dt = softplus(x_dbc[:, :64] @ w_dt + b_dt)   [4096,64]@[64,2048]
    gemm_f32<1><<<dim3(32, 64), 256, 0, stream>>>(
        dbc, w_dt, dtb, b_dt, MTOT, DINNER, DTRANK, 96, DINNER, DINNER);

    // 5) chunked selective scan + gating -> yp
    scan_phase_a<<<(NCHUNK * BDN) / 256, 256, 0, stream>>>(dtb, xc, dbc, A_log, Sb, Pl);
    scan_phase_b<<<BDN / 256, 256, 0, stream>>>(Sb, Pl, Hc);
    scan_phase_c<<<(NCHUNK * BDN) / 256, 256, 0, stream>>>(dtb, xc, dbc, xz, A_log, Dvec, Hc, yp);

    // 6) out-projection: out = yp @ w_out      [4096,2048]@[2048,1024]
    gemm_f32<0><<<dim3(16, 64), 256, 0, stream>>>(
        yp, w_out, out, nullptr, MTOT, DMODEL, DINNER, DINNER, DMODEL, DMODEL);
}

// Round 3
// 839.697 us; speedup vs baseline: 2.5241x; 1.4290x over previous
//
#include <hip/hip_runtime.h>
#include <math.h>

#define SEQ    2048
#define BSZ    2
#define DMODEL 1024
#define DINNER 2048
#define DSTATE 16
#define DTRANK 64
#define MTOT   (BSZ*SEQ)   // 4096
#define NCHUNK 16
#define LC     (SEQ/NCHUNK)   // 128
#define BDN    (BSZ*DINNER*DSTATE)  // 65536

using frag8 = __attribute__((ext_vector_type(8))) short;   // 8 bf16
using f32x4 = __attribute__((ext_vector_type(4))) float;

// ---------- bf16 split helpers ----------
__device__ __forceinline__ unsigned short bf16_rn(float x) {
    unsigned u = __float_as_uint(x);
    u += 0x7fffu + ((u >> 16) & 1u);
    return (unsigned short)(u >> 16);
}
__device__ __forceinline__ float bf16_to_f(unsigned short h) {
    return __uint_as_float(((unsigned)h) << 16);
}

// ---------------- MFMA bf16 GEMM, B pre-transposed: C[M,N] = A[M,Kp] @ BT[N,Kp]^T ----------------
// 128x128 tile, BK=32, 256 threads (4 waves 2x2), 16x16x32 MFMA, global_load_lds staging.
__global__ __launch_bounds__(256)
void gemm_bt_bf16(const unsigned short* __restrict__ A, const unsigned short* __restrict__ BT,
                  float* __restrict__ C, int Kp, int N)
{
    __shared__ unsigned short Asm[128 * 32];   // 8KB
    __shared__ unsigned short Bsm[128 * 32];   // 8KB
    const int tid  = threadIdx.x;
    const int wave = tid >> 6, lane = tid & 63;
    const int m0 = blockIdx.y * 128, n0 = blockIdx.x * 128;
    const int wm = (wave >> 1) * 64, wn = (wave & 1) * 64;

    // staging: lane -> local row lane>>2 (16 rows/wave/round), swizzled k-chunk
    const int srow = lane >> 2;
    const int sq   = (lane & 3) ^ ((srow >> 1) & 3);
    // compute-side fragment addressing: row fr, swizzled chunk fq
    const int fr = lane & 15;
    const int fq = (lane >> 4) ^ ((fr >> 1) & 3);

    f32x4 acc[4][4];
    #pragma unroll
    for (int i = 0; i < 4; ++i)
        #pragma unroll
        for (int j = 0; j < 4; ++j)
            acc[i][j] = (f32x4){0.f, 0.f, 0.f, 0.f};

    for (int k0 = 0; k0 < Kp; k0 += 32) {
        __syncthreads();
        #pragma unroll
        for (int r = 0; r < 2; ++r) {
            const int trow = (wave * 2 + r) * 16 + srow;     // 0..127
            const unsigned short* ga = A  + (size_t)(m0 + trow) * Kp + k0 + sq * 8;
            const unsigned short* gb = BT + (size_t)(n0 + trow) * Kp + k0 + sq * 8;
            unsigned short* la = Asm + (wave * 2 + r) * 512; // 16 rows * 32 ushort
            unsigned short* lb = Bsm + (wave * 2 + r) * 512;
            __builtin_amdgcn_global_load_lds(
                (const __attribute__((address_space(1))) unsigned int*)(const void*)ga,
                (__attribute__((address_space(3))) unsigned int*)(void*)la, 16, 0, 0);
            __builtin_amdgcn_global_load_lds(
                (const __attribute__((address_space(1))) unsigned int*)(const void*)gb,
                (__attribute__((address_space(3))) unsigned int*)(void*)lb, 16, 0, 0);
        }
        __syncthreads();
        frag8 av[4], bv[4];
        #pragma unroll
        for (int i = 0; i < 4; ++i)
            av[i] = *(const frag8*)(Asm + (wm + i * 16 + fr) * 32 + fq * 8);
        #pragma unroll
        for (int j = 0; j < 4; ++j)
            bv[j] = *(const frag8*)(Bsm + (wn + j * 16 + fr) * 32 + fq * 8);
        #pragma unroll
        for (int i = 0; i < 4; ++i)
            #pragma unroll
            for (int j = 0; j < 4; ++j)
                acc[i][j] = __builtin_amdgcn_mfma_f32_16x16x32_bf16(av[i], bv[j], acc[i][j], 0, 0, 0);
    }

    // C/D layout: col = lane&15, row = (lane>>4)*4 + reg
    const int crow = (lane >> 4) * 4, ccol = lane & 15;
    #pragma unroll
    for (int i = 0; i < 4; ++i)
        #pragma unroll
        for (int j = 0; j < 4; ++j)
            #pragma unroll
            for (int v = 0; v < 4; ++v) {
                const int row = m0 + wm + i * 16 + crow + v;
                const int col = n0 + wn + j * 16 + ccol;
                C[(size_t)row * N + col] = acc[i][j][v];
            }
}

// ---------------- conversions ----------------
// A (row-major [R][K]) -> Ap [R][3K] = [hi | lo | hi]
__global__ __launch_bounds__(256)
void cvt_a(const float* __restrict__ A, unsigned short* __restrict__ Ap, int K)
{
    const int idx = blockIdx.x * 256 + threadIdx.x;   // float4 groups
    const int kq = K >> 2;
    const int row = idx / kq, c4 = idx % kq;
    float4 v = ((const float4*)A)[idx];
    float f[4] = {v.x, v.y, v.z, v.w};
    unsigned short h[4], l[4];
    #pragma unroll
    for (int i = 0; i < 4; ++i) {
        h[i] = bf16_rn(f[i]);
        l[i] = bf16_rn(f[i] - bf16_to_f(h[i]));
    }
    const size_t base = (size_t)row * 3 * K + c4 * 4;
    *(ushort4*)(Ap + base)         = make_ushort4(h[0], h[1], h[2], h[3]);
    *(ushort4*)(Ap + base + K)     = make_ushort4(l[0], l[1], l[2], l[3]);
    *(ushort4*)(Ap + base + 2 * K) = make_ushort4(h[0], h[1], h[2], h[3]);
}

// B [K][N] -> BTp [N][3K] = [hi | hi | lo]  (64x64 LDS tile transpose)
__global__ __launch_bounds__(256)
void cvt_bt(const float* __restrict__ B, unsigned short* __restrict__ BTp, int K, int N)
{
    __shared__ float t[64][65];
    const int bk = blockIdx.x * 64, bn = blockIdx.y * 64;
    const int tid = threadIdx.x;
    {
        const int r = tid >> 4, c4 = (tid & 15) * 4;
        #pragma unroll
        for (int p = 0; p < 4; ++p) {
            float4 v = *(const float4*)(B + (size_t)(bk + p * 16 + r) * N + bn + c4);
            t[p * 16 + r][c4 + 0] = v.x;
            t[p * 16 + r][c4 + 1] = v.y;
            t[p * 16 + r][c4 + 2] = v.z;
            t[p * 16 + r][c4 + 3] = v.w;
        }
    }
    __syncthreads();
    const int nl = tid >> 2, kc = (tid & 3) * 16;
    unsigned short h[16], l[16];
    #pragma unroll
    for (int i = 0; i < 16; ++i) {
        const float x = t[kc + i][nl];
        h[i] = bf16_rn(x);
        l[i] = bf16_rn(x - bf16_to_f(h[i]));
    }
    unsigned hw[8], lw[8];
    #pragma unroll
    for (int j = 0; j < 8; ++j) {
        hw[j] = (unsigned)h[2 * j] | ((unsigned)h[2 * j + 1] << 16);
        lw[j] = (unsigned)l[2 * j] | ((unsigned)l[2 * j + 1] << 16);
    }
    unsigned short* dst = BTp + (size_t)(bn + nl) * 3 * K + bk + kc;
    *(uint4*)(dst)              = make_uint4(hw[0], hw[1], hw[2], hw[3]);
    *(uint4*)(dst + 8)          = make_uint4(hw[4], hw[5], hw[6], hw[7]);
    *(uint4*)(dst + K)          = make_uint4(hw[0], hw[1], hw[2], hw[3]);
    *(uint4*)(dst + K + 8)      = make_uint4(hw[4], hw[5], hw[6], hw[7]);
    *(uint4*)(dst + 2 * K)      = make_uint4(lw[0], lw[1], lw[2], lw[3]);
    *(uint4*)(dst + 2 * K + 8)  = make_uint4(lw[4], lw[5], lw[6], lw[7]);
}

// ---------------- generic fp32 tiled GEMM (small ops only) ----------------
template<int EPI>
__global__ __launch_bounds__(256)
void gemm_f32(const float* __restrict__ A, const float* __restrict__ B,
              float* __restrict__ C, const float* __restrict__ bias,
              int M, int N, int K, int lda, int ldb, int ldc)
{
    __shared__ float As[16][68];
    __shared__ float Bs[16][68];
    const int tid = threadIdx.x;
    const int tx = tid & 15, ty = tid >> 4;
    const int m0 = blockIdx.y * 64, n0 = blockIdx.x * 64;
    const int arow = tid >> 2, acol = (tid & 3) << 2;
    const int brow = tid >> 4, bcol = (tid & 15) << 2;
    float acc[4][4] = {{0.f,0.f,0.f,0.f},{0.f,0.f,0.f,0.f},
                       {0.f,0.f,0.f,0.f},{0.f,0.f,0.f,0.f}};

    for (int k0 = 0; k0 < K; k0 += 16) {
        float4 av = *(const float4*)(A + (size_t)(m0 + arow) * lda + k0 + acol);
        float4 bv = make_float4(0.f, 0.f, 0.f, 0.f);
        if (n0 + bcol < N)
            bv = *(const float4*)(B + (size_t)(k0 + brow) * ldb + n0 + bcol);
        __syncthreads();
        As[acol+0][arow] = av.x;
        As[acol+1][arow] = av.y;
        As[acol+2][arow] = av.z;
        As[acol+3][arow] = av.w;
        *(float4*)&Bs[brow][bcol] = bv;
        __syncthreads();
        #pragma unroll
        for (int kk = 0; kk < 16; ++kk) {
            float4 a = *(const float4*)&As[kk][ty << 2];
            float4 b = *(const float4*)&Bs[kk][tx << 2];
            float ar[4] = {a.x, a.y, a.z, a.w};
            float br[4] = {b.x, b.y, b.z, b.w};
            #pragma unroll
            for (int i = 0; i < 4; ++i)
                #pragma unroll
                for (int j = 0; j < 4; ++j)
                    acc[i][j] = fmaf(ar[i], br[j], acc[i][j]);
        }
    }

    const int col = n0 + (tx << 2);
    if (col >= N) return;
    #pragma unroll
    for (int i = 0; i < 4; ++i) {
        const int row = m0 + (ty << 2) + i;
        float r[4] = {acc[i][0], acc[i][1], acc[i][2], acc[i][3]};
        if (EPI == 1) {
            #pragma unroll
            for (int j = 0; j < 4; ++j) {
                float xb = r[j] + bias[col + j];
                r[j] = fmaxf(xb, 0.f) + log1pf(expf(-fabsf(xb)));
            }
        }
        float4 o; o.x = r[0]; o.y = r[1]; o.z = r[2]; o.w = r[3];
        *(float4*)(C + (size_t)row * ldc + col) = o;
    }
}

// ---------------- causal depthwise conv (k=4) + silu ----------------
__global__ __launch_bounds__(256)
void conv_silu_k(const float* __restrict__ xz, const float* __restrict__ wconv,
                 const float* __restrict__ bconv, float* __restrict__ xc)
{
    const int idx = blockIdx.x * 256 + threadIdx.x;
    const int d   = idx & (DINNER - 1);
    const int row = idx >> 11;
    const int l   = row & (SEQ - 1);
    const float4 w = *(const float4*)(wconv + d * 4);
    const float wk[4] = {w.x, w.y, w.z, w.w};
    float acc = bconv[d];
    const float* xp = xz + (size_t)row * (2 * DINNER) + d;
    #pragma unroll
    for (int k = 0; k < 4; ++k) {
        const int ls = l - 3 + k;
        if (ls >= 0) acc = fmaf(xp[(k - 3) * (2 * DINNER)], wk[k], acc);
    }
    xc[idx] = acc / (1.f + expf(-acc));
}

// ---------------- chunked selective scan ----------------
__global__ __launch_bounds__(256)
void scan_phase_a(const float* __restrict__ dtb, const float* __restrict__ xc,
                  const float* __restrict__ dbc, const float* __restrict__ A_log,
                  float* __restrict__ S, float* __restrict__ Pl)
{
    const int tid = blockIdx.x * 256 + threadIdx.x;
    const int bdn = tid & (BDN - 1);
    const int c   = tid >> 16;
    const int n = bdn & 15;
    const int d = (bdn >> 4) & (DINNER - 1);
    const int b = bdn >> 15;
    const float a = -expf(A_log[d * DSTATE + n]);
    const int r0 = b * SEQ + c * LC;
    const float* dtp = dtb + (size_t)r0 * DINNER + d;
    const float* xcp = xc  + (size_t)r0 * DINNER + d;
    const float* bp  = dbc + (size_t)r0 * 96 + DTRANK + n;
    float h = 0.f, sdt = 0.f;
    for (int l = 0; l < LC; l += 8) {
        float dtv[8], xv[8], Bv[8];
        #pragma unroll
        for (int j = 0; j < 8; ++j) {
            dtv[j] = dtp[(size_t)(l + j) * DINNER];
            xv[j]  = xcp[(size_t)(l + j) * DINNER];
            Bv[j]  = bp[(size_t)(l + j) * 96];
        }
        #pragma unroll
        for (int j = 0; j < 8; ++j) {
            sdt += dtv[j];
            h = expf(dtv[j] * a) * h + (xv[j] * dtv[j]) * Bv[j];
        }
    }
    S[tid]  = h;
    Pl[tid] = a * sdt;
}

__global__ __launch_bounds__(256)
void scan_phase_b(const float* __restrict__ S, const float* __restrict__ Pl,
                  float* __restrict__ H)
{
    const int bdn = blockIdx.x * 256 + threadIdx.x;
    float h = 0.f;
    #pragma unroll
    for (int c = 0; c < NCHUNK; ++c) {
        H[c * BDN + bdn] = h;
        h = expf(Pl[c * BDN + bdn]) * h + S[c * BDN + bdn];
    }
}

__global__ __launch_bounds__(256)
void scan_phase_c(const float* __restrict__ dtb, const float* __restrict__ xc,
                  const float* __restrict__ dbc, const float* __restrict__ xz,
                  const float* __restrict__ A_log, const float* __restrict__ Dvec,
                  const float* __restrict__ H, float* __restrict__ y)
{
    const int tid = blockIdx.x * 256 + threadIdx.x;
    const int bdn = tid & (BDN - 1);
    const int c   = tid >> 16;
    const int n = bdn & 15;
    const int d = (bdn >> 4) & (DINNER - 1);
    const int b = bdn >> 15;
    const float a  = -expf(A_log[d * DSTATE + n]);
    const float Dv = Dvec[d];
    const int r0 = b * SEQ + c * LC;
    const float* dtp = dtb + (size_t)r0 * DINNER + d;
    const float* xcp = xc  + (size_t)r0 * DINNER + d;
    const float* bp  = dbc + (size_t)r0 * 96 + DTRANK + n;
    const float* cp  = dbc + (size_t)r0 * 96 + DTRANK + DSTATE + n;
    const float* zp  = xz  + (size_t)r0 * (2 * DINNER) + DINNER + d;
    float*       yp  = y   + (size_t)r0 * DINNER + d;
    float h = H[tid];

    for (int l = 0; l < LC; l += 8) {
        float dtv[8], xv[8], Bv[8], Cv[8], p[8];
        #pragma unroll
        for (int j = 0; j < 8; ++j) {
            dtv[j] = dtp[(size_t)(l + j) * DINNER];
            xv[j]  = xcp[(size_t)(l + j) * DINNER];
            Bv[j]  = bp[(size_t)(l + j) * 96];
            Cv[j]  = cp[(size_t)(l + j) * 96];
        }
        #pragma unroll
        for (int j = 0; j < 8; ++j) {
            h = expf(dtv[j] * a) * h + (xv[j] * dtv[j]) * Bv[j];
            p[j] = Cv[j] * h;
        }
        #pragma unroll
        for (int m = 1; m < 16; m <<= 1) {
            #pragma unroll
            for (int j = 0; j < 8; ++j)
                p[j] += __shfl_xor(p[j], m);
        }
        if (n == 0) {
            #pragma unroll
            for (int j = 0; j < 8; ++j) {
                const float zv = zp[(size_t)(l + j) * (2 * DINNER)];
                const float s  = zv / (1.f + expf(-zv));
                yp[(size_t)(l + j) * DINNER] = (p[j] + xv[j] * Dv) * s;
            }
        }
    }
}

extern "C" void kernel_launch(void* const* d_in, const int* in_sizes, int n_in,
                              void* d_out, int out_size, void* d_ws, size_t ws_size,
                              hipStream_t stream)
{
    const float* x      = (const float*)d_in[0];
    const float* w_in   = (const float*)d_in[1];
    const float* w_conv = (const float*)d_in[2];
    const float* b_conv = (const float*)d_in[3];
    const float* w_xproj= (const float*)d_in[4];
    const float* w_dt   = (const float*)d_in[5];
    const float* b_dt   = (const float*)d_in[6];
    const float* A_log  = (const float*)d_in[7];
    const float* Dvec   = (const float*)d_in[8];
    const float* w_out  = (const float*)d_in[9];
    float* out = (float*)d_out;

    float* ws  = (float*)d_ws;
    float* xz  = ws;                                  // [4096,4096]  67.1 MB
    float* xc  = xz  + (size_t)MTOT * 2 * DINNER;     // [4096,2048]  33.5 MB
    float* dbc = xc  + (size_t)MTOT * DINNER;         // [4096,96]     1.6 MB
    float* dtb = dbc + (size_t)MTOT * 96;             // [4096,2048]  33.5 MB
    float* yp  = dtb + (size_t)MTOT * DINNER;         // [4096,2048]  33.5 MB
    float* Sb  = yp  + (size_t)MTOT * DINNER;         // [16,65536]
    float* Pl  = Sb  + (size_t)NCHUNK * BDN;
    float* Hc  = Pl  + (size_t)NCHUNK * BDN;

    // aliased bf16 staging (dead regions):
    // x_pk + w_in_pk live only until in-proj completes -> overlay dtb/yp region
    unsigned short* x_pk  = (unsigned short*)dtb;                         // [4096][3*1024]
    unsigned short* wi_pk = x_pk + (size_t)MTOT * 3 * DMODEL;             // [4096][3*1024]
    // yp_pk + w_out_pk live only after scan C (xz dead) -> overlay xz
    unsigned short* yp_pk = (unsigned short*)xz;                          // [4096][3*2048]
    unsigned short* wo_pk = yp_pk + (size_t)MTOT * 3 * DINNER;            // [1024][3*2048]

    // 1) in-projection: xz = x @ w_in  via split-bf16 MFMA (Kp = 3*1024)
    cvt_a <<<(MTOT * DMODEL / 4) / 256, 256, 0, stream>>>(x, x_pk, DMODEL);
    cvt_bt<<<dim3(DMODEL / 64, (2 * DINNER) / 64), 256, 0, stream>>>(w_in, wi_pk, DMODEL, 2 * DINNER);
    gemm_bt_bf16<<<dim3((2 * DINNER) / 128, MTOT / 128), 256, 0, stream>>>(
        x_pk, wi_pk, xz, 3 * DMODEL, 2 * DINNER);

    // 2) causal conv + silu -> xc
    conv_silu_k<<<(MTOT * DINNER) / 256, 256, 0, stream>>>(xz, w_conv, b_conv, xc);

    // 3) x_dbc = xc @ w_xproj   [4096,2048]@[2048,96]
    gemm_f32<0><<<dim3(2, 64), 256, 0, stream>>>(
        xc, w_xproj, dbc, nullptr, MTOT, 96, DINNER, DINNER, 96, 96);

    // 4) dt = softplus(x_dbc[:, :64] @ w_dt + b_dt)
    gemm_f32<1><<<dim3(32, 64), 256, 0, stream>>>(
        dbc, w_dt, dtb, b_dt, MTOT, DINNER, DTRANK, 96, DINNER, DINNER);

    // 5) chunked selective scan + gating -> yp
    scan_phase_a<<<(NCHUNK * BDN) / 256, 256, 0, stream>>>(dtb, xc, dbc, A_log, Sb, Pl);
    scan_phase_b<<<BDN / 256, 256, 0, stream>>>(Sb, Pl, Hc);
    scan_phase_c<<<(NCHUNK * BDN) / 256, 256, 0, stream>>>(dtb, xc, dbc, xz, A_log, Dvec, Hc, yp);

    // 6) out-projection: out = yp @ w_out  via split-bf16 MFMA (Kp = 3*2048)
    cvt_a <<<(MTOT * DINNER / 4) / 256, 256, 0, stream>>>(yp, yp_pk, DINNER);
    cvt_bt<<<dim3(DINNER / 64, DMODEL / 64), 256, 0, stream>>>(w_out, wo_pk, DINNER, DMODEL);
    gemm_bt_bf16<<<dim3(DMODEL / 128, MTOT / 128), 256, 0, stream>>>(
        yp_pk, wo_pk, out, 3 * DINNER, DMODEL);
}

// Round 4
// 598.231 us; speedup vs baseline: 3.5429x; 1.4036x over previous
//
#include <hip/hip_runtime.h>
#include <math.h>

#define SEQ    2048
#define BSZ    2
#define DMODEL 1024
#define DINNER 2048
#define DSTATE 16
#define DTRANK 64
#define MTOT   (BSZ*SEQ)   // 4096
#define NCHUNK 16
#define LC     (SEQ/NCHUNK)   // 128
#define BDN    (BSZ*DINNER*DSTATE)  // 65536
#define KSPLIT 8

using frag8 = __attribute__((ext_vector_type(8))) short;   // 8 bf16
using f32x4 = __attribute__((ext_vector_type(4))) float;

__device__ __forceinline__ float fast_rcp(float x) { return __builtin_amdgcn_rcpf(x); }

// ---------- bf16 split helpers ----------
__device__ __forceinline__ unsigned short bf16_rn(float x) {
    unsigned u = __float_as_uint(x);
    u += 0x7fffu + ((u >> 16) & 1u);
    return (unsigned short)(u >> 16);
}
__device__ __forceinline__ float bf16_to_f(unsigned short h) {
    return __uint_as_float(((unsigned)h) << 16);
}

// ---------------- MFMA bf16 GEMM, B pre-transposed: C[M,N] = A[M,Kp] @ BT[N,Kp]^T ----------------
__global__ __launch_bounds__(256)
void gemm_bt_bf16(const unsigned short* __restrict__ A, const unsigned short* __restrict__ BT,
                  float* __restrict__ C, int Kp, int N)
{
    __shared__ unsigned short Asm[128 * 32];
    __shared__ unsigned short Bsm[128 * 32];
    const int tid  = threadIdx.x;
    const int wave = tid >> 6, lane = tid & 63;
    const int m0 = blockIdx.y * 128, n0 = blockIdx.x * 128;
    const int wm = (wave >> 1) * 64, wn = (wave & 1) * 64;

    const int srow = lane >> 2;
    const int sq   = (lane & 3) ^ ((srow >> 1) & 3);
    const int fr = lane & 15;
    const int fq = (lane >> 4) ^ ((fr >> 1) & 3);

    f32x4 acc[4][4];
    #pragma unroll
    for (int i = 0; i < 4; ++i)
        #pragma unroll
        for (int j = 0; j < 4; ++j)
            acc[i][j] = (f32x4){0.f, 0.f, 0.f, 0.f};

    for (int k0 = 0; k0 < Kp; k0 += 32) {
        __syncthreads();
        #pragma unroll
        for (int r = 0; r < 2; ++r) {
            const int trow = (wave * 2 + r) * 16 + srow;
            const unsigned short* ga = A  + (size_t)(m0 + trow) * Kp + k0 + sq * 8;
            const unsigned short* gb = BT + (size_t)(n0 + trow) * Kp + k0 + sq * 8;
            unsigned short* la = Asm + (wave * 2 + r) * 512;
            unsigned short* lb = Bsm + (wave * 2 + r) * 512;
            __builtin_amdgcn_global_load_lds(
                (const __attribute__((address_space(1))) unsigned int*)(const void*)ga,
                (__attribute__((address_space(3))) unsigned int*)(void*)la, 16, 0, 0);
            __builtin_amdgcn_global_load_lds(
                (const __attribute__((address_space(1))) unsigned int*)(const void*)gb,
                (__attribute__((address_space(3))) unsigned int*)(void*)lb, 16, 0, 0);
        }
        __syncthreads();
        frag8 av[4], bv[4];
        #pragma unroll
        for (int i = 0; i < 4; ++i)
            av[i] = *(const frag8*)(Asm + (wm + i * 16 + fr) * 32 + fq * 8);
        #pragma unroll
        for (int j = 0; j < 4; ++j)
            bv[j] = *(const frag8*)(Bsm + (wn + j * 16 + fr) * 32 + fq * 8);
        #pragma unroll
        for (int i = 0; i < 4; ++i)
            #pragma unroll
            for (int j = 0; j < 4; ++j)
                acc[i][j] = __builtin_amdgcn_mfma_f32_16x16x32_bf16(av[i], bv[j], acc[i][j], 0, 0, 0);
    }

    const int crow = (lane >> 4) * 4, ccol = lane & 15;
    #pragma unroll
    for (int i = 0; i < 4; ++i)
        #pragma unroll
        for (int j = 0; j < 4; ++j)
            #pragma unroll
            for (int v = 0; v < 4; ++v) {
                const int row = m0 + wm + i * 16 + crow + v;
                const int col = n0 + wn + j * 16 + ccol;
                C[(size_t)row * N + col] = acc[i][j][v];
            }
}

// ---------------- conversions ----------------
__global__ __launch_bounds__(256)
void cvt_a(const float* __restrict__ A, unsigned short* __restrict__ Ap, int K)
{
    const int idx = blockIdx.x * 256 + threadIdx.x;
    const int kq = K >> 2;
    const int row = idx / kq, c4 = idx % kq;
    float4 v = ((const float4*)A)[idx];
    float f[4] = {v.x, v.y, v.z, v.w};
    unsigned short h[4], l[4];
    #pragma unroll
    for (int i = 0; i < 4; ++i) {
        h[i] = bf16_rn(f[i]);
        l[i] = bf16_rn(f[i] - bf16_to_f(h[i]));
    }
    const size_t base = (size_t)row * 3 * K + c4 * 4;
    *(ushort4*)(Ap + base)         = make_ushort4(h[0], h[1], h[2], h[3]);
    *(ushort4*)(Ap + base + K)     = make_ushort4(l[0], l[1], l[2], l[3]);
    *(ushort4*)(Ap + base + 2 * K) = make_ushort4(h[0], h[1], h[2], h[3]);
}

__global__ __launch_bounds__(256)
void cvt_bt(const float* __restrict__ B, unsigned short* __restrict__ BTp, int K, int N)
{
    __shared__ float t[64][65];
    const int bk = blockIdx.x * 64, bn = blockIdx.y * 64;
    const int tid = threadIdx.x;
    {
        const int r = tid >> 4, c4 = (tid & 15) * 4;
        #pragma unroll
        for (int p = 0; p < 4; ++p) {
            float4 v = *(const float4*)(B + (size_t)(bk + p * 16 + r) * N + bn + c4);
            t[p * 16 + r][c4 + 0] = v.x;
            t[p * 16 + r][c4 + 1] = v.y;
            t[p * 16 + r][c4 + 2] = v.z;
            t[p * 16 + r][c4 + 3] = v.w;
        }
    }
    __syncthreads();
    const int nl = tid >> 2, kc = (tid & 3) * 16;
    unsigned short h[16], l[16];
    #pragma unroll
    for (int i = 0; i < 16; ++i) {
        const float x = t[kc + i][nl];
        h[i] = bf16_rn(x);
        l[i] = bf16_rn(x - bf16_to_f(h[i]));
    }
    unsigned hw[8], lw[8];
    #pragma unroll
    for (int j = 0; j < 8; ++j) {
        hw[j] = (unsigned)h[2 * j] | ((unsigned)h[2 * j + 1] << 16);
        lw[j] = (unsigned)l[2 * j] | ((unsigned)l[2 * j + 1] << 16);
    }
    unsigned short* dst = BTp + (size_t)(bn + nl) * 3 * K + bk + kc;
    *(uint4*)(dst)              = make_uint4(hw[0], hw[1], hw[2], hw[3]);
    *(uint4*)(dst + 8)          = make_uint4(hw[4], hw[5], hw[6], hw[7]);
    *(uint4*)(dst + K)          = make_uint4(hw[0], hw[1], hw[2], hw[3]);
    *(uint4*)(dst + K + 8)      = make_uint4(hw[4], hw[5], hw[6], hw[7]);
    *(uint4*)(dst + 2 * K)      = make_uint4(lw[0], lw[1], lw[2], lw[3]);
    *(uint4*)(dst + 2 * K + 8)  = make_uint4(lw[4], lw[5], lw[6], lw[7]);
}

// ---------------- generic fp32 tiled GEMM ----------------
// EPI: 0 plain, 1 softplus(acc+bias)
template<int EPI>
__global__ __launch_bounds__(256)
void gemm_f32(const float* __restrict__ A, const float* __restrict__ B,
              float* __restrict__ C, const float* __restrict__ bias,
              int M, int N, int K, int lda, int ldb, int ldc)
{
    __shared__ float As[16][68];
    __shared__ float Bs[16][68];
    const int tid = threadIdx.x;
    const int tx = tid & 15, ty = tid >> 4;
    const int m0 = blockIdx.y * 64, n0 = blockIdx.x * 64;
    const int arow = tid >> 2, acol = (tid & 3) << 2;
    const int brow = tid >> 4, bcol = (tid & 15) << 2;
    float acc[4][4] = {{0.f,0.f,0.f,0.f},{0.f,0.f,0.f,0.f},
                       {0.f,0.f,0.f,0.f},{0.f,0.f,0.f,0.f}};

    for (int k0 = 0; k0 < K; k0 += 16) {
        float4 av = *(const float4*)(A + (size_t)(m0 + arow) * lda + k0 + acol);
        float4 bv = make_float4(0.f, 0.f, 0.f, 0.f);
        if (n0 + bcol < N)
            bv = *(const float4*)(B + (size_t)(k0 + brow) * ldb + n0 + bcol);
        __syncthreads();
        As[acol+0][arow] = av.x;
        As[acol+1][arow] = av.y;
        As[acol+2][arow] = av.z;
        As[acol+3][arow] = av.w;
        *(float4*)&Bs[brow][bcol] = bv;
        __syncthreads();
        #pragma unroll
        for (int kk = 0; kk < 16; ++kk) {
            float4 a = *(const float4*)&As[kk][ty << 2];
            float4 b = *(const float4*)&Bs[kk][tx << 2];
            float ar[4] = {a.x, a.y, a.z, a.w};
            float br[4] = {b.x, b.y, b.z, b.w};
            #pragma unroll
            for (int i = 0; i < 4; ++i)
                #pragma unroll
                for (int j = 0; j < 4; ++j)
                    acc[i][j] = fmaf(ar[i], br[j], acc[i][j]);
        }
    }

    const int col = n0 + (tx << 2);
    if (col >= N) return;
    #pragma unroll
    for (int i = 0; i < 4; ++i) {
        const int row = m0 + (ty << 2) + i;
        float r[4] = {acc[i][0], acc[i][1], acc[i][2], acc[i][3]};
        if (EPI == 1) {
            #pragma unroll
            for (int j = 0; j < 4; ++j) {
                float xb = r[j] + bias[col + j];
                r[j] = fmaxf(xb, 0.f) + log1pf(expf(-fabsf(xb)));
            }
        }
        float4 o; o.x = r[0]; o.y = r[1]; o.z = r[2]; o.w = r[3];
        *(float4*)(C + (size_t)row * ldc + col) = o;
    }
}

// ---------------- split-K fp32 GEMM for the skinny xproj (N=96) ----------------
// grid (2, M/64, KSPLIT); writes partials P[z][M][96]
__global__ __launch_bounds__(256)
void gemm_f32_sk(const float* __restrict__ A, const float* __restrict__ B,
                 float* __restrict__ P, int M, int N, int Ktot, int lda, int ldb)
{
    __shared__ float As[16][68];
    __shared__ float Bs[16][68];
    const int tid = threadIdx.x;
    const int tx = tid & 15, ty = tid >> 4;
    const int m0 = blockIdx.y * 64, n0 = blockIdx.x * 64;
    const int z = blockIdx.z;
    const int ks = Ktot / KSPLIT;
    const int kbeg = z * ks, kend = kbeg + ks;
    const int arow = tid >> 2, acol = (tid & 3) << 2;
    const int brow = tid >> 4, bcol = (tid & 15) << 2;
    float acc[4][4] = {{0.f,0.f,0.f,0.f},{0.f,0.f,0.f,0.f},
                       {0.f,0.f,0.f,0.f},{0.f,0.f,0.f,0.f}};

    for (int k0 = kbeg; k0 < kend; k0 += 16) {
        float4 av = *(const float4*)(A + (size_t)(m0 + arow) * lda + k0 + acol);
        float4 bv = make_float4(0.f, 0.f, 0.f, 0.f);
        if (n0 + bcol < N)
            bv = *(const float4*)(B + (size_t)(k0 + brow) * ldb + n0 + bcol);
        __syncthreads();
        As[acol+0][arow] = av.x;
        As[acol+1][arow] = av.y;
        As[acol+2][arow] = av.z;
        As[acol+3][arow] = av.w;
        *(float4*)&Bs[brow][bcol] = bv;
        __syncthreads();
        #pragma unroll
        for (int kk = 0; kk < 16; ++kk) {
            float4 a = *(const float4*)&As[kk][ty << 2];
            float4 b = *(const float4*)&Bs[kk][tx << 2];
            float ar[4] = {a.x, a.y, a.z, a.w};
            float br[4] = {b.x, b.y, b.z, b.w};
            #pragma unroll
            for (int i = 0; i < 4; ++i)
                #pragma unroll
                for (int j = 0; j < 4; ++j)
                    acc[i][j] = fmaf(ar[i], br[j], acc[i][j]);
        }
    }

    const int col = n0 + (tx << 2);
    if (col >= N) return;
    float* Pz = P + (size_t)z * M * 96;
    #pragma unroll
    for (int i = 0; i < 4; ++i) {
        const int row = m0 + (ty << 2) + i;
        float4 o; o.x = acc[i][0]; o.y = acc[i][1]; o.z = acc[i][2]; o.w = acc[i][3];
        *(float4*)(Pz + (size_t)row * 96 + col) = o;
    }
}

__global__ __launch_bounds__(256)
void reduce_sk(const float* __restrict__ P, float* __restrict__ C, int total4)
{
    const int i = blockIdx.x * 256 + threadIdx.x;
    if (i >= total4) return;
    float4 s = ((const float4*)P)[i];
    #pragma unroll
    for (int z = 1; z < KSPLIT; ++z) {
        float4 v = ((const float4*)(P + (size_t)z * total4 * 4))[i];
        s.x += v.x; s.y += v.y; s.z += v.z; s.w += v.w;
    }
    ((float4*)C)[i] = s;
}

// ---------------- causal depthwise conv (k=4) + silu ----------------
__global__ __launch_bounds__(256)
void conv_silu_k(const float* __restrict__ xz, const float* __restrict__ wconv,
                 const float* __restrict__ bconv, float* __restrict__ xc)
{
    const int idx = blockIdx.x * 256 + threadIdx.x;
    const int d   = idx & (DINNER - 1);
    const int row = idx >> 11;
    const int l   = row & (SEQ - 1);
    const float4 w = *(const float4*)(wconv + d * 4);
    const float wk[4] = {w.x, w.y, w.z, w.w};
    float acc = bconv[d];
    const float* xp = xz + (size_t)row * (2 * DINNER) + d;
    #pragma unroll
    for (int k = 0; k < 4; ++k) {
        const int ls = l - 3 + k;
        if (ls >= 0) acc = fmaf(xp[(k - 3) * (2 * DINNER)], wk[k], acc);
    }
    xc[idx] = acc * fast_rcp(1.f + __expf(-acc));
}

// ---------------- chunked selective scan, 4 states per thread ----------------
// thread tid: ng = tid&3 (n = ng*4..ng*4+3), d = (tid>>2)&2047, b = (tid>>13)&1, c = tid>>14
__global__ __launch_bounds__(256)
void scan_phase_a(const float* __restrict__ dtb, const float* __restrict__ xc,
                  const float* __restrict__ dbc, const float* __restrict__ A_log,
                  float* __restrict__ S, float* __restrict__ Pl)
{
    const int tid = blockIdx.x * 256 + threadIdx.x;   // 262144
    const int ng = tid & 3;
    const int d  = (tid >> 2) & (DINNER - 1);
    const int b  = (tid >> 13) & 1;
    const int c  = tid >> 14;
    float a[4];
    #pragma unroll
    for (int i = 0; i < 4; ++i)
        a[i] = -__expf(A_log[d * DSTATE + ng * 4 + i]);
    const int r0 = b * SEQ + c * LC;
    const float* dtp = dtb + (size_t)r0 * DINNER + d;
    const float* xcp = xc  + (size_t)r0 * DINNER + d;
    const float* bp  = dbc + (size_t)r0 * 96 + DTRANK + ng * 4;
    float h[4] = {0.f, 0.f, 0.f, 0.f};
    float sdt = 0.f;

    for (int l = 0; l < LC; l += 4) {
        float dtv[4], xv[4];
        float4 Bv[4];
        #pragma unroll
        for (int j = 0; j < 4; ++j) {
            dtv[j] = dtp[(size_t)(l + j) * DINNER];
            xv[j]  = xcp[(size_t)(l + j) * DINNER];
            Bv[j]  = *(const float4*)(bp + (size_t)(l + j) * 96);
        }
        #pragma unroll
        for (int j = 0; j < 4; ++j) {
            sdt += dtv[j];
            const float xd = xv[j] * dtv[j];
            const float Bf[4] = {Bv[j].x, Bv[j].y, Bv[j].z, Bv[j].w};
            #pragma unroll
            for (int i = 0; i < 4; ++i)
                h[i] = __expf(dtv[j] * a[i]) * h[i] + xd * Bf[i];
        }
    }
    const size_t off = (size_t)c * BDN + b * (DINNER * DSTATE) + d * DSTATE + ng * 4;
    float4 hv; hv.x = h[0]; hv.y = h[1]; hv.z = h[2]; hv.w = h[3];
    float4 pv; pv.x = a[0] * sdt; pv.y = a[1] * sdt; pv.z = a[2] * sdt; pv.w = a[3] * sdt;
    *(float4*)(S + off)  = hv;
    *(float4*)(Pl + off) = pv;
}

__global__ __launch_bounds__(256)
void scan_phase_b(const float* __restrict__ S, const float* __restrict__ Pl,
                  float* __restrict__ H)
{
    const int bdn = blockIdx.x * 256 + threadIdx.x;
    float h = 0.f;
    #pragma unroll
    for (int c = 0; c < NCHUNK; ++c) {
        H[c * BDN + bdn] = h;
        h = __expf(Pl[c * BDN + bdn]) * h + S[c * BDN + bdn];
    }
}

__global__ __launch_bounds__(256)
void scan_phase_c(const float* __restrict__ dtb, const float* __restrict__ xc,
                  const float* __restrict__ dbc, const float* __restrict__ xz,
                  const float* __restrict__ A_log, const float* __restrict__ Dvec,
                  const float* __restrict__ H, float* __restrict__ y)
{
    const int tid = blockIdx.x * 256 + threadIdx.x;   // 262144
    const int ng = tid & 3;
    const int d  = (tid >> 2) & (DINNER - 1);
    const int b  = (tid >> 13) & 1;
    const int c  = tid >> 14;
    float a[4];
    #pragma unroll
    for (int i = 0; i < 4; ++i)
        a[i] = -__expf(A_log[d * DSTATE + ng * 4 + i]);
    const float Dv = Dvec[d];
    const int r0 = b * SEQ + c * LC;
    const float* dtp = dtb + (size_t)r0 * DINNER + d;
    const float* xcp = xc  + (size_t)r0 * DINNER + d;
    const float* bp  = dbc + (size_t)r0 * 96 + DTRANK + ng * 4;
    const float* cp  = dbc + (size_t)r0 * 96 + DTRANK + DSTATE + ng * 4;
    const float* zp  = xz  + (size_t)r0 * (2 * DINNER) + DINNER + d;
    float*       yp  = y   + (size_t)r0 * DINNER + d;

    const size_t off = (size_t)c * BDN + b * (DINNER * DSTATE) + d * DSTATE + ng * 4;
    float4 h0 = *(const float4*)(H + off);
    float h[4] = {h0.x, h0.y, h0.z, h0.w};

    for (int l = 0; l < LC; l += 4) {
        float dtv[4], xv[4], p[4];
        float4 Bv[4], Cv[4];
        #pragma unroll
        for (int j = 0; j < 4; ++j) {
            dtv[j] = dtp[(size_t)(l + j) * DINNER];
            xv[j]  = xcp[(size_t)(l + j) * DINNER];
            Bv[j]  = *(const float4*)(bp + (size_t)(l + j) * 96);
            Cv[j]  = *(const float4*)(cp + (size_t)(l + j) * 96);
        }
        #pragma unroll
        for (int j = 0; j < 4; ++j) {
            const float xd = xv[j] * dtv[j];
            const float Bf[4] = {Bv[j].x, Bv[j].y, Bv[j].z, Bv[j].w};
            #pragma unroll
            for (int i = 0; i < 4; ++i)
                h[i] = __expf(dtv[j] * a[i]) * h[i] + xd * Bf[i];
            p[j] = h[0] * Cv[j].x + h[1] * Cv[j].y + h[2] * Cv[j].z + h[3] * Cv[j].w;
        }
        // sum over the 4 ng lanes (lanes differ in bits 0..1)
        #pragma unroll
        for (int j = 0; j < 4; ++j) {
            p[j] += __shfl_xor(p[j], 1);
            p[j] += __shfl_xor(p[j], 2);
        }
        // each ng-lane stores its own step (no masked-off lanes)
        const float psel = (ng == 0) ? p[0] : (ng == 1) ? p[1] : (ng == 2) ? p[2] : p[3];
        const float xsel = (ng == 0) ? xv[0] : (ng == 1) ? xv[1] : (ng == 2) ? xv[2] : xv[3];
        const float zv = zp[(size_t)(l + ng) * (2 * DINNER)];
        const float s  = zv * fast_rcp(1.f + __expf(-zv));
        yp[(size_t)(l + ng) * DINNER] = (psel + xsel * Dv) * s;
    }
}

extern "C" void kernel_launch(void* const* d_in, const int* in_sizes, int n_in,
                              void* d_out, int out_size, void* d_ws, size_t ws_size,
                              hipStream_t stream)
{
    const float* x      = (const float*)d_in[0];
    const float* w_in   = (const float*)d_in[1];
    const float* w_conv = (const float*)d_in[2];
    const float* b_conv = (const float*)d_in[3];
    const float* w_xproj= (const float*)d_in[4];
    const float* w_dt   = (const float*)d_in[5];
    const float* b_dt   = (const float*)d_in[6];
    const float* A_log  = (const float*)d_in[7];
    const float* Dvec   = (const float*)d_in[8];
    const float* w_out  = (const float*)d_in[9];
    float* out = (float*)d_out;

    float* ws  = (float*)d_ws;
    float* xz  = ws;                                  // [4096,4096]
    float* xc  = xz  + (size_t)MTOT * 2 * DINNER;     // [4096,2048]
    float* dbc = xc  + (size_t)MTOT * DINNER;         // [4096,96]
    float* dtb = dbc + (size_t)MTOT * 96;             // [4096,2048]
    float* yp  = dtb + (size_t)MTOT * DINNER;         // [4096,2048]
    float* Sb  = yp  + (size_t)MTOT * DINNER;         // [16,65536]
    float* Pl  = Sb  + (size_t)NCHUNK * BDN;
    float* Hc  = Pl  + (size_t)NCHUNK * BDN;

    // aliased staging over dead regions
    unsigned short* x_pk  = (unsigned short*)dtb;                 // in-proj staging
    unsigned short* wi_pk = x_pk + (size_t)MTOT * 3 * DMODEL;
    unsigned short* yp_pk = (unsigned short*)xz;                  // out-proj staging
    unsigned short* wo_pk = yp_pk + (size_t)MTOT * 3 * DINNER;
    float* Psk = dtb;   // split-K partials [8][4096][96] (dead window before dtb is written)

    // 1) in-projection: xz = x @ w_in  (split-bf16 MFMA)
    cvt_a <<<(MTOT * DMODEL / 4) / 256, 256, 0, stream>>>(x, x_pk, DMODEL);
    cvt_bt<<<dim3(DMODEL / 64, (2 * DINNER) / 64), 256, 0, stream>>>(w_in, wi_pk, DMODEL, 2 * DINNER);
    gemm_bt_bf16<<<dim3((2 * DINNER) / 128, MTOT / 128), 256, 0, stream>>>(
        x_pk, wi_pk, xz, 3 * DMODEL, 2 * DINNER);

    // 2) causal conv + silu -> xc
    conv_silu_k<<<(MTOT * DINNER) / 256, 256, 0, stream>>>(xz, w_conv, b_conv, xc);

    // 3) x_dbc = xc @ w_xproj  (split-K, deterministic two-stage)
    gemm_f32_sk<<<dim3(2, 64, KSPLIT), 256, 0, stream>>>(
        xc, w_xproj, Psk, MTOT, 96, DINNER, DINNER, 96);
    reduce_sk<<<(MTOT * 96 / 4 + 255) / 256, 256, 0, stream>>>(Psk, dbc, MTOT * 96 / 4);

    // 4) dt = softplus(x_dbc[:, :64] @ w_dt + b_dt)
    gemm_f32<1><<<dim3(32, 64), 256, 0, stream>>>(
        dbc, w_dt, dtb, b_dt, MTOT, DINNER, DTRANK, 96, DINNER, DINNER);

    // 5) chunked selective scan + gating -> yp
    scan_phase_a<<<(NCHUNK * BSZ * DINNER * 4) / 256, 256, 0, stream>>>(dtb, xc, dbc, A_log, Sb, Pl);
    scan_phase_b<<<BDN / 256, 256, 0, stream>>>(Sb, Pl, Hc);
    scan_phase_c<<<(NCHUNK * BSZ * DINNER * 4) / 256, 256, 0, stream>>>(dtb, xc, dbc, xz, A_log, Dvec, Hc, yp);

    // 6) out-projection: out = yp @ w_out  (split-bf16 MFMA)
    cvt_a <<<(MTOT * DINNER / 4) / 256, 256, 0, stream>>>(yp, yp_pk, DINNER);
    cvt_bt<<<dim3(DINNER / 64, DMODEL / 64), 256, 0, stream>>>(w_out, wo_pk, DINNER, DMODEL);
    gemm_bt_bf16<<<dim3(DMODEL / 128, MTOT / 128), 256, 0, stream>>>(
        yp_pk, wo_pk, out, 3 * DINNER, DMODEL);
}

// Round 5
// 484.145 us; speedup vs baseline: 4.3778x; 1.2356x over previous
//
#include <hip/hip_runtime.h>
#include <math.h>

#define SEQ    2048
#define BSZ    2
#define DMODEL 1024
#define DINNER 2048
#define DSTATE 16
#define DTRANK 64
#define MTOT   (BSZ*SEQ)   // 4096
#define NCHUNK 16
#define LC     (SEQ/NCHUNK)   // 128
#define BDN    (BSZ*DINNER*DSTATE)  // 65536
#define KSPLIT 8

using frag8h = __attribute__((ext_vector_type(8))) _Float16;  // 8 fp16 (4 VGPRs)
using f32x4  = __attribute__((ext_vector_type(4))) float;

__device__ __forceinline__ float fast_rcp(float x) { return __builtin_amdgcn_rcpf(x); }

// ---------- fp16 helpers (RN casts) ----------
__device__ __forceinline__ unsigned short f16_bits(float x) {
    _Float16 h = (_Float16)x;
    unsigned short u; __builtin_memcpy(&u, &h, 2); return u;
}
__device__ __forceinline__ float f16_val(unsigned short u) {
    _Float16 h; __builtin_memcpy(&h, &u, 2); return (float)h;
}

// ---------------- MFMA fp16 GEMM, B pre-transposed, optional split-K ----------------
// C[M,N] = A[M,Kp] @ BT[N,Kp]^T over K-range [z*klen, (z+1)*klen), partial -> C + z*M*N
// 128x128 tile, BK=32, 256 threads (4 waves 2x2), 16x16x32 f16 MFMA, global_load_lds.
__global__ __launch_bounds__(256)
void gemm_bt_f16(const unsigned short* __restrict__ A, const unsigned short* __restrict__ BT,
                 float* __restrict__ C, int Kp, int N, int klen)
{
    __shared__ unsigned short Asm[128 * 32];   // 8KB
    __shared__ unsigned short Bsm[128 * 32];   // 8KB
    const int tid  = threadIdx.x;
    const int wave = tid >> 6, lane = tid & 63;
    const int m0 = blockIdx.y * 128, n0 = blockIdx.x * 128;
    const int wm = (wave >> 1) * 64, wn = (wave & 1) * 64;
    const int M = gridDim.y * 128;
    float* Cz = C + (size_t)blockIdx.z * M * N;
    const int kbeg = blockIdx.z * klen, kend = kbeg + klen;

    // staging: lane -> local row lane>>2, swizzled k-chunk
    const int srow = lane >> 2;
    const int sq   = (lane & 3) ^ ((srow >> 1) & 3);
    // compute-side fragment addressing
    const int fr = lane & 15;
    const int fq = (lane >> 4) ^ ((fr >> 1) & 3);

    f32x4 acc[4][4];
    #pragma unroll
    for (int i = 0; i < 4; ++i)
        #pragma unroll
        for (int j = 0; j < 4; ++j)
            acc[i][j] = (f32x4){0.f, 0.f, 0.f, 0.f};

    for (int k0 = kbeg; k0 < kend; k0 += 32) {
        __syncthreads();
        #pragma unroll
        for (int r = 0; r < 2; ++r) {
            const int trow = (wave * 2 + r) * 16 + srow;
            const unsigned short* ga = A  + (size_t)(m0 + trow) * Kp + k0 + sq * 8;
            const unsigned short* gb = BT + (size_t)(n0 + trow) * Kp + k0 + sq * 8;
            unsigned short* la = Asm + (wave * 2 + r) * 512;
            unsigned short* lb = Bsm + (wave * 2 + r) * 512;
            __builtin_amdgcn_global_load_lds(
                (const __attribute__((address_space(1))) unsigned int*)(const void*)ga,
                (__attribute__((address_space(3))) unsigned int*)(void*)la, 16, 0, 0);
            __builtin_amdgcn_global_load_lds(
                (const __attribute__((address_space(1))) unsigned int*)(const void*)gb,
                (__attribute__((address_space(3))) unsigned int*)(void*)lb, 16, 0, 0);
        }
        __syncthreads();
        frag8h av[4], bv[4];
        #pragma unroll
        for (int i = 0; i < 4; ++i)
            av[i] = *(const frag8h*)(Asm + (wm + i * 16 + fr) * 32 + fq * 8);
        #pragma unroll
        for (int j = 0; j < 4; ++j)
            bv[j] = *(const frag8h*)(Bsm + (wn + j * 16 + fr) * 32 + fq * 8);
        #pragma unroll
        for (int i = 0; i < 4; ++i)
            #pragma unroll
            for (int j = 0; j < 4; ++j)
                acc[i][j] = __builtin_amdgcn_mfma_f32_16x16x32_f16(av[i], bv[j], acc[i][j], 0, 0, 0);
    }

    // C/D layout: col = lane&15, row = (lane>>4)*4 + reg
    const int crow = (lane >> 4) * 4, ccol = lane & 15;
    #pragma unroll
    for (int i = 0; i < 4; ++i)
        #pragma unroll
        for (int j = 0; j < 4; ++j)
            #pragma unroll
            for (int v = 0; v < 4; ++v) {
                const int row = m0 + wm + i * 16 + crow + v;
                const int col = n0 + wn + j * 16 + ccol;
                Cz[(size_t)row * N + col] = acc[i][j][v];
            }
}

// ---------------- conversions (fp16 2-product packing) ----------------
// A (row-major [R][K]) -> Ap [R][2K] = [hi | lo]
__global__ __launch_bounds__(256)
void cvt_a_h2(const float* __restrict__ A, unsigned short* __restrict__ Ap, int K)
{
    const int idx = blockIdx.x * 256 + threadIdx.x;   // float4 groups
    const int kq = K >> 2;
    const int row = idx / kq, c4 = idx % kq;
    float4 v = ((const float4*)A)[idx];
    float f[4] = {v.x, v.y, v.z, v.w};
    unsigned short h[4], l[4];
    #pragma unroll
    for (int i = 0; i < 4; ++i) {
        h[i] = f16_bits(f[i]);
        l[i] = f16_bits(f[i] - f16_val(h[i]));
    }
    const size_t base = (size_t)row * 2 * K + c4 * 4;
    *(ushort4*)(Ap + base)     = make_ushort4(h[0], h[1], h[2], h[3]);
    *(ushort4*)(Ap + base + K) = make_ushort4(l[0], l[1], l[2], l[3]);
}

// B [K][N] -> BTp [N][2K] = [hi | hi]  (64x64 LDS tile transpose)
__global__ __launch_bounds__(256)
void cvt_bt_h2(const float* __restrict__ B, unsigned short* __restrict__ BTp, int K, int N)
{
    __shared__ float t[64][65];
    const int bk = blockIdx.x * 64, bn = blockIdx.y * 64;
    const int tid = threadIdx.x;
    {
        const int r = tid >> 4, c4 = (tid & 15) * 4;
        #pragma unroll
        for (int p = 0; p < 4; ++p) {
            float4 v = *(const float4*)(B + (size_t)(bk + p * 16 + r) * N + bn + c4);
            t[p * 16 + r][c4 + 0] = v.x;
            t[p * 16 + r][c4 + 1] = v.y;
            t[p * 16 + r][c4 + 2] = v.z;
            t[p * 16 + r][c4 + 3] = v.w;
        }
    }
    __syncthreads();
    const int nl = tid >> 2, kc = (tid & 3) * 16;
    unsigned short h[16];
    #pragma unroll
    for (int i = 0; i < 16; ++i)
        h[i] = f16_bits(t[kc + i][nl]);
    unsigned hw[8];
    #pragma unroll
    for (int j = 0; j < 8; ++j)
        hw[j] = (unsigned)h[2 * j] | ((unsigned)h[2 * j + 1] << 16);
    unsigned short* dst = BTp + (size_t)(bn + nl) * 2 * K + bk + kc;
    *(uint4*)(dst)         = make_uint4(hw[0], hw[1], hw[2], hw[3]);
    *(uint4*)(dst + 8)     = make_uint4(hw[4], hw[5], hw[6], hw[7]);
    *(uint4*)(dst + K)     = make_uint4(hw[0], hw[1], hw[2], hw[3]);
    *(uint4*)(dst + K + 8) = make_uint4(hw[4], hw[5], hw[6], hw[7]);
}

// ---------------- generic fp32 tiled GEMM (dt-proj only) ----------------
template<int EPI>
__global__ __launch_bounds__(256)
void gemm_f32(const float* __restrict__ A, const float* __restrict__ B,
              float* __restrict__ C, const float* __restrict__ bias,
              int M, int N, int K, int lda, int ldb, int ldc)
{
    __shared__ float As[16][68];
    __shared__ float Bs[16][68];
    const int tid = threadIdx.x;
    const int tx = tid & 15, ty = tid >> 4;
    const int m0 = blockIdx.y * 64, n0 = blockIdx.x * 64;
    const int arow = tid >> 2, acol = (tid & 3) << 2;
    const int brow = tid >> 4, bcol = (tid & 15) << 2;
    float acc[4][4] = {{0.f,0.f,0.f,0.f},{0.f,0.f,0.f,0.f},
                       {0.f,0.f,0.f,0.f},{0.f,0.f,0.f,0.f}};

    for (int k0 = 0; k0 < K; k0 += 16) {
        float4 av = *(const float4*)(A + (size_t)(m0 + arow) * lda + k0 + acol);
        float4 bv = make_float4(0.f, 0.f, 0.f, 0.f);
        if (n0 + bcol < N)
            bv = *(const float4*)(B + (size_t)(k0 + brow) * ldb + n0 + bcol);
        __syncthreads();
        As[acol+0][arow] = av.x;
        As[acol+1][arow] = av.y;
        As[acol+2][arow] = av.z;
        As[acol+3][arow] = av.w;
        *(float4*)&Bs[brow][bcol] = bv;
        __syncthreads();
        #pragma unroll
        for (int kk = 0; kk < 16; ++kk) {
            float4 a = *(const float4*)&As[kk][ty << 2];
            float4 b = *(const float4*)&Bs[kk][tx << 2];
            float ar[4] = {a.x, a.y, a.z, a.w};
            float br[4] = {b.x, b.y, b.z, b.w};
            #pragma unroll
            for (int i = 0; i < 4; ++i)
                #pragma unroll
                for (int j = 0; j < 4; ++j)
                    acc[i][j] = fmaf(ar[i], br[j], acc[i][j]);
        }
    }

    const int col = n0 + (tx << 2);
    if (col >= N) return;
    #pragma unroll
    for (int i = 0; i < 4; ++i) {
        const int row = m0 + (ty << 2) + i;
        float r[4] = {acc[i][0], acc[i][1], acc[i][2], acc[i][3]};
        if (EPI == 1) {
            #pragma unroll
            for (int j = 0; j < 4; ++j) {
                float xb = r[j] + bias[col + j];
                r[j] = fmaxf(xb, 0.f) + log1pf(expf(-fabsf(xb)));
            }
        }
        float4 o; o.x = r[0]; o.y = r[1]; o.z = r[2]; o.w = r[3];
        *(float4*)(C + (size_t)row * ldc + col) = o;
    }
}

// ---------------- split-K fp32 GEMM for the skinny xproj (N=96) ----------------
__global__ __launch_bounds__(256)
void gemm_f32_sk(const float* __restrict__ A, const float* __restrict__ B,
                 float* __restrict__ P, int M, int N, int Ktot, int lda, int ldb)
{
    __shared__ float As[16][68];
    __shared__ float Bs[16][68];
    const int tid = threadIdx.x;
    const int tx = tid & 15, ty = tid >> 4;
    const int m0 = blockIdx.y * 64, n0 = blockIdx.x * 64;
    const int z = blockIdx.z;
    const int ks = Ktot / KSPLIT;
    const int kbeg = z * ks, kend = kbeg + ks;
    const int arow = tid >> 2, acol = (tid & 3) << 2;
    const int brow = tid >> 4, bcol = (tid & 15) << 2;
    float acc[4][4] = {{0.f,0.f,0.f,0.f},{0.f,0.f,0.f,0.f},
                       {0.f,0.f,0.f,0.f},{0.f,0.f,0.f,0.f}};

    for (int k0 = kbeg; k0 < kend; k0 += 16) {
        float4 av = *(const float4*)(A + (size_t)(m0 + arow) * lda + k0 + acol);
        float4 bv = make_float4(0.f, 0.f, 0.f, 0.f);
        if (n0 + bcol < N)
            bv = *(const float4*)(B + (size_t)(k0 + brow) * ldb + n0 + bcol);
        __syncthreads();
        As[acol+0][arow] = av.x;
        As[acol+1][arow] = av.y;
        As[acol+2][arow] = av.z;
        As[acol+3][arow] = av.w;
        *(float4*)&Bs[brow][bcol] = bv;
        __syncthreads();
        #pragma unroll
        for (int kk = 0; kk < 16; ++kk) {
            float4 a = *(const float4*)&As[kk][ty << 2];
            float4 b = *(const float4*)&Bs[kk][tx << 2];
            float ar[4] = {a.x, a.y, a.z, a.w};
            float br[4] = {b.x, b.y, b.z, b.w};
            #pragma unroll
            for (int i = 0; i < 4; ++i)
                #pragma unroll
                for (int j = 0; j < 4; ++j)
                    acc[i][j] = fmaf(ar[i], br[j], acc[i][j]);
        }
    }

    const int col = n0 + (tx << 2);
    if (col >= N) return;
    float* Pz = P + (size_t)z * M * 96;
    #pragma unroll
    for (int i = 0; i < 4; ++i) {
        const int row = m0 + (ty << 2) + i;
        float4 o; o.x = acc[i][0]; o.y = acc[i][1]; o.z = acc[i][2]; o.w = acc[i][3];
        *(float4*)(Pz + (size_t)row * 96 + col) = o;
    }
}

template<int NS>
__global__ __launch_bounds__(256)
void reduce_add(const float* __restrict__ P, float* __restrict__ C, int total4)
{
    const int i = blockIdx.x * 256 + threadIdx.x;
    if (i >= total4) return;
    float4 s = ((const float4*)P)[i];
    #pragma unroll
    for (int z = 1; z < NS; ++z) {
        float4 v = ((const float4*)P)[(size_t)z * total4 + i];
        s.x += v.x; s.y += v.y; s.z += v.z; s.w += v.w;
    }
    ((float4*)C)[i] = s;
}

// ---------------- causal depthwise conv (k=4) + silu ----------------
__global__ __launch_bounds__(256)
void conv_silu_k(const float* __restrict__ xz, const float* __restrict__ wconv,
                 const float* __restrict__ bconv, float* __restrict__ xc)
{
    const int idx = blockIdx.x * 256 + threadIdx.x;
    const int d   = idx & (DINNER - 1);
    const int row = idx >> 11;
    const int l   = row & (SEQ - 1);
    const float4 w = *(const float4*)(wconv + d * 4);
    const float wk[4] = {w.x, w.y, w.z, w.w};
    float acc = bconv[d];
    const float* xp = xz + (size_t)row * (2 * DINNER) + d;
    #pragma unroll
    for (int k = 0; k < 4; ++k) {
        const int ls = l - 3 + k;
        if (ls >= 0) acc = fmaf(xp[(k - 3) * (2 * DINNER)], wk[k], acc);
    }
    xc[idx] = acc * fast_rcp(1.f + __expf(-acc));
}

// ---------------- chunked selective scan, 4 states per thread ----------------
__global__ __launch_bounds__(256)
void scan_phase_a(const float* __restrict__ dtb, const float* __restrict__ xc,
                  const float* __restrict__ dbc, const float* __restrict__ A_log,
                  float* __restrict__ S, float* __restrict__ Pl)
{
    const int tid = blockIdx.x * 256 + threadIdx.x;   // 262144
    const int ng = tid & 3;
    const int d  = (tid >> 2) & (DINNER - 1);
    const int b  = (tid >> 13) & 1;
    const int c  = tid >> 14;
    float a[4];
    #pragma unroll
    for (int i = 0; i < 4; ++i)
        a[i] = -__expf(A_log[d * DSTATE + ng * 4 + i]);
    const int r0 = b * SEQ + c * LC;
    const float* dtp = dtb + (size_t)r0 * DINNER + d;
    const float* xcp = xc  + (size_t)r0 * DINNER + d;
    const float* bp  = dbc + (size_t)r0 * 96 + DTRANK + ng * 4;
    float h[4] = {0.f, 0.f, 0.f, 0.f};
    float sdt = 0.f;

    for (int l = 0; l < LC; l += 4) {
        float dtv[4], xv[4];
        float4 Bv[4];
        #pragma unroll
        for (int j = 0; j < 4; ++j) {
            dtv[j] = dtp[(size_t)(l + j) * DINNER];
            xv[j]  = xcp[(size_t)(l + j) * DINNER];
            Bv[j]  = *(const float4*)(bp + (size_t)(l + j) * 96);
        }
        #pragma unroll
        for (int j = 0; j < 4; ++j) {
            sdt += dtv[j];
            const float xd = xv[j] * dtv[j];
            const float Bf[4] = {Bv[j].x, Bv[j].y, Bv[j].z, Bv[j].w};
            #pragma unroll
            for (int i = 0; i < 4; ++i)
                h[i] = __expf(dtv[j] * a[i]) * h[i] + xd * Bf[i];
        }
    }
    const size_t off = (size_t)c * BDN + b * (DINNER * DSTATE) + d * DSTATE + ng * 4;
    float4 hv; hv.x = h[0]; hv.y = h[1]; hv.z = h[2]; hv.w = h[3];
    float4 pv; pv.x = a[0] * sdt; pv.y = a[1] * sdt; pv.z = a[2] * sdt; pv.w = a[3] * sdt;
    *(float4*)(S + off)  = hv;
    *(float4*)(Pl + off) = pv;
}

__global__ __launch_bounds__(256)
void scan_phase_b(const float* __restrict__ S, const float* __restrict__ Pl,
                  float* __restrict__ H)
{
    const int bdn = blockIdx.x * 256 + threadIdx.x;
    float h = 0.f;
    #pragma unroll
    for (int c = 0; c < NCHUNK; ++c) {
        H[c * BDN + bdn] = h;
        h = __expf(Pl[c * BDN + bdn]) * h + S[c * BDN + bdn];
    }
}

// Phase C: gated output written directly in fp16 [hi|lo] packed rows [row][2*DINNER]
__global__ __launch_bounds__(256)
void scan_phase_c(const float* __restrict__ dtb, const float* __restrict__ xc,
                  const float* __restrict__ dbc, const float* __restrict__ xz,
                  const float* __restrict__ A_log, const float* __restrict__ Dvec,
                  const float* __restrict__ H, unsigned short* __restrict__ ypk)
{
    const int tid = blockIdx.x * 256 + threadIdx.x;   // 262144
    const int ng = tid & 3;
    const int d  = (tid >> 2) & (DINNER - 1);
    const int b  = (tid >> 13) & 1;
    const int c  = tid >> 14;
    float a[4];
    #pragma unroll
    for (int i = 0; i < 4; ++i)
        a[i] = -__expf(A_log[d * DSTATE + ng * 4 + i]);
    const float Dv = Dvec[d];
    const int r0 = b * SEQ + c * LC;
    const float* dtp = dtb + (size_t)r0 * DINNER + d;
    const float* xcp = xc  + (size_t)r0 * DINNER + d;
    const float* bp  = dbc + (size_t)r0 * 96 + DTRANK + ng * 4;
    const float* cp  = dbc + (size_t)r0 * 96 + DTRANK + DSTATE + ng * 4;
    const float* zp  = xz  + (size_t)r0 * (2 * DINNER) + DINNER + d;

    const size_t off = (size_t)c * BDN + b * (DINNER * DSTATE) + d * DSTATE + ng * 4;
    float4 h0 = *(const float4*)(H + off);
    float h[4] = {h0.x, h0.y, h0.z, h0.w};

    for (int l = 0; l < LC; l += 4) {
        float dtv[4], xv[4], p[4];
        float4 Bv[4], Cv[4];
        #pragma unroll
        for (int j = 0; j < 4; ++j) {
            dtv[j] = dtp[(size_t)(l + j) * DINNER];
            xv[j]  = xcp[(size_t)(l + j) * DINNER];
            Bv[j]  = *(const float4*)(bp + (size_t)(l + j) * 96);
            Cv[j]  = *(const float4*)(cp + (size_t)(l + j) * 96);
        }
        #pragma unroll
        for (int j = 0; j < 4; ++j) {
            const float xd = xv[j] * dtv[j];
            const float Bf[4] = {Bv[j].x, Bv[j].y, Bv[j].z, Bv[j].w};
            #pragma unroll
            for (int i = 0; i < 4; ++i)
                h[i] = __expf(dtv[j] * a[i]) * h[i] + xd * Bf[i];
            p[j] = h[0] * Cv[j].x + h[1] * Cv[j].y + h[2] * Cv[j].z + h[3] * Cv[j].w;
        }
        #pragma unroll
        for (int j = 0; j < 4; ++j) {
            p[j] += __shfl_xor(p[j], 1);
            p[j] += __shfl_xor(p[j], 2);
        }
        const float psel = (ng == 0) ? p[0] : (ng == 1) ? p[1] : (ng == 2) ? p[2] : p[3];
        const float xsel = (ng == 0) ? xv[0] : (ng == 1) ? xv[1] : (ng == 2) ? xv[2] : xv[3];
        const float zv = zp[(size_t)(l + ng) * (2 * DINNER)];
        const float s  = zv * fast_rcp(1.f + __expf(-zv));
        const float v  = (psel + xsel * Dv) * s;
        const unsigned short hb = f16_bits(v);
        const unsigned short lb = f16_bits(v - f16_val(hb));
        const size_t rr = (size_t)(r0 + l + ng) * (2 * DINNER) + d;
        ypk[rr]          = hb;
        ypk[rr + DINNER] = lb;
    }
}

extern "C" void kernel_launch(void* const* d_in, const int* in_sizes, int n_in,
                              void* d_out, int out_size, void* d_ws, size_t ws_size,
                              hipStream_t stream)
{
    const float* x      = (const float*)d_in[0];
    const float* w_in   = (const float*)d_in[1];
    const float* w_conv = (const float*)d_in[2];
    const float* b_conv = (const float*)d_in[3];
    const float* w_xproj= (const float*)d_in[4];
    const float* w_dt   = (const float*)d_in[5];
    const float* b_dt   = (const float*)d_in[6];
    const float* A_log  = (const float*)d_in[7];
    const float* Dvec   = (const float*)d_in[8];
    const float* w_out  = (const float*)d_in[9];
    float* out = (float*)d_out;

    float* ws  = (float*)d_ws;
    float* xz  = ws;                                  // [4096,4096]  67.1 MB
    float* xc  = xz  + (size_t)MTOT * 2 * DINNER;     // [4096,2048]  33.5 MB
    float* dbc = xc  + (size_t)MTOT * DINNER;         // [4096,96]     1.6 MB
    float* dtb = dbc + (size_t)MTOT * 96;             // [4096,2048]  33.5 MB
    float* Sb  = dtb + (size_t)MTOT * DINNER;         // [16,65536]    4.2 MB
    float* Pl  = Sb  + (size_t)NCHUNK * BDN;          //               4.2 MB
    float* Hc  = Pl  + (size_t)NCHUNK * BDN;          //               4.2 MB
    float* R1  = Hc  + (size_t)NCHUNK * BDN;          //              33.6 MB shared region

    // Region aliasing (liveness-checked):
    // R1: [x_pk | wi_pk] (steps 1-3) then yp_pk (step 7+)
    unsigned short* x_pk  = (unsigned short*)R1;                      // [4096][2048] f16
    unsigned short* wi_pk = x_pk + (size_t)MTOT * 2 * DMODEL;         // [4096][2048] f16
    unsigned short* yp_pk = (unsigned short*)R1;                      // [4096][4096] f16
    // dtb region: Psk (step 5, before dtb written) then Pout (step 9, after scans)
    float* Psk  = dtb;   // [8][4096][96]  12.6 MB
    float* Pout = dtb;   // [2][4096][1024] 33.5 MB
    // Sb+Pl region: wo_pk (step 8+, after scan_b consumed them)
    unsigned short* wo_pk = (unsigned short*)Sb;                      // [1024][4096] f16 = 8.4 MB

    // 1-2) pack x and w_in for fp16 2-product GEMM
    cvt_a_h2 <<<(MTOT * DMODEL / 4) / 256, 256, 0, stream>>>(x, x_pk, DMODEL);
    cvt_bt_h2<<<dim3(DMODEL / 64, (2 * DINNER) / 64), 256, 0, stream>>>(w_in, wi_pk, DMODEL, 2 * DINNER);

    // 3) in-projection: xz = x @ w_in   (Kp = 2*1024, no split-K)
    gemm_bt_f16<<<dim3((2 * DINNER) / 128, MTOT / 128, 1), 256, 0, stream>>>(
        x_pk, wi_pk, xz, 2 * DMODEL, 2 * DINNER, 2 * DMODEL);

    // 4) causal conv + silu -> xc
    conv_silu_k<<<(MTOT * DINNER) / 256, 256, 0, stream>>>(xz, w_conv, b_conv, xc);

    // 5) x_dbc = xc @ w_xproj  (split-K fp32, deterministic two-stage)
    gemm_f32_sk<<<dim3(2, 64, KSPLIT), 256, 0, stream>>>(
        xc, w_xproj, Psk, MTOT, 96, DINNER, DINNER, 96);
    reduce_add<KSPLIT><<<(MTOT * 96 / 4 + 255) / 256, 256, 0, stream>>>(Psk, dbc, MTOT * 96 / 4);

    // 6) dt = softplus(x_dbc[:, :64] @ w_dt + b_dt)
    gemm_f32<1><<<dim3(32, 64), 256, 0, stream>>>(
        dbc, w_dt, dtb, b_dt, MTOT, DINNER, DTRANK, 96, DINNER, DINNER);

    // 7) chunked selective scan + gating -> yp_pk (packed fp16 [hi|lo])
    scan_phase_a<<<(NCHUNK * BSZ * DINNER * 4) / 256, 256, 0, stream>>>(dtb, xc, dbc, A_log, Sb, Pl);
    scan_phase_b<<<BDN / 256, 256, 0, stream>>>(Sb, Pl, Hc);
    scan_phase_c<<<(NCHUNK * BSZ * DINNER * 4) / 256, 256, 0, stream>>>(dtb, xc, dbc, xz, A_log, Dvec, Hc, yp_pk);

    // 8) pack w_out
    cvt_bt_h2<<<dim3(DINNER / 64, DMODEL / 64), 256, 0, stream>>>(w_out, wo_pk, DINNER, DMODEL);

    // 9) out-projection: out = yp @ w_out  (Kp = 2*2048, split-K=2 -> partials)
    gemm_bt_f16<<<dim3(DMODEL / 128, MTOT / 128, 2), 256, 0, stream>>>(
        yp_pk, wo_pk, Pout, 2 * DINNER, DMODEL, DINNER);
    reduce_add<2><<<(MTOT * DMODEL / 4 + 255) / 256, 256, 0, stream>>>(Pout, out, MTOT * DMODEL / 4);
}